// Round 1
// baseline (214.522 us; speedup 1.0000x reference)
//
#include <hip/hip_runtime.h>
#include <math.h>

#define DCOL 8192
#define PNUM 1024
#define BATCH 256
#define HISTLEN 101
#define WIN 10
#define NK 5
#define EPSF 1e-6f

// ws layout (float offsets)
#define WS_RECENT 0                     // 10*8192 floats
#define WS_RINV   (WIN*DCOL)            // 81920, 5*8192 floats
#define WS_STR    (WS_RINV + NK*DCOL)   // 122880, 1024 floats
#define WS_PART   131072                // split-K partials, SPL*256*1024 floats

// ---------------------------------------------------------------------------
// K0: build `recent` (last 10 history rows with row hist_idx replaced by
// input_spikes[0]) and rinv[k][d] = 1/(sqrt(sum_w K2[k][w]*recent^2)+eps)
// ---------------------------------------------------------------------------
__global__ __launch_bounds__(256) void k0_prep(
    const float* __restrict__ spikes, const float* __restrict__ hist,
    const float* __restrict__ ck, const int* __restrict__ hidxp,
    float* __restrict__ ws)
{
  const int g = blockIdx.x * 256 + threadIdx.x;   // 0..2047
  const int col = g * 4;
  int hidx = hidxp[0] % HISTLEN;
  if (hidx < 0) hidx += HISTLEN;

  float k2[NK][WIN];
#pragma unroll
  for (int k = 0; k < NK; ++k)
#pragma unroll
    for (int w = 0; w < WIN; ++w) { float v = ck[k*WIN + w]; k2[k][w] = v * v; }

  float rn[NK][4];
#pragma unroll
  for (int k = 0; k < NK; ++k)
#pragma unroll
    for (int j = 0; j < 4; ++j) rn[k][j] = 0.f;

#pragma unroll
  for (int w = 0; w < WIN; ++w) {
    const int row = HISTLEN - WIN + w;            // 91..100
    const float* src = (row == hidx) ? spikes : (hist + (size_t)row * DCOL);
    const float4 r = *(const float4*)(src + col);
    *(float4*)(ws + WS_RECENT + w*DCOL + col) = r;
    const float rr[4] = { r.x, r.y, r.z, r.w };
#pragma unroll
    for (int k = 0; k < NK; ++k)
#pragma unroll
      for (int j = 0; j < 4; ++j) rn[k][j] += k2[k][w] * rr[j] * rr[j];
  }

#pragma unroll
  for (int k = 0; k < NK; ++k) {
    float o[4];
#pragma unroll
    for (int j = 0; j < 4; ++j) o[j] = 1.0f / (sqrtf(rn[k][j]) + EPSF);
    float4 v; v.x = o[0]; v.y = o[1]; v.z = o[2]; v.w = o[3];
    *(float4*)(ws + WS_RINV + k*DCOL + col) = v;
  }
}

// ---------------------------------------------------------------------------
// K1: strength[p] = mean over (k,d) of num*rinv/(sqrt(tn)+eps).
// One block per pattern p; 320 KB of templates read per block (HBM-bound).
// ---------------------------------------------------------------------------
__global__ __launch_bounds__(256) void k1_strength(
    const float* __restrict__ templ, const float* __restrict__ ck,
    const float* __restrict__ recent, const float* __restrict__ rinv,
    float* __restrict__ strength)
{
  const int p = blockIdx.x;
  const int tid = threadIdx.x;

  float k2[NK][WIN];
#pragma unroll
  for (int k = 0; k < NK; ++k)
#pragma unroll
    for (int w = 0; w < WIN; ++w) { float v = ck[k*WIN + w]; k2[k][w] = v * v; }

  const float* __restrict__ tbase = templ + (size_t)p * WIN * DCOL;
  float acc[4] = {0.f, 0.f, 0.f, 0.f};

  for (int c = 0; c < DCOL/(256*4); ++c) {        // 8 chunks of 1024 cols
    const int col = (c * 256 + tid) * 4;
    float num[NK][4], tn[NK][4];
#pragma unroll
    for (int k = 0; k < NK; ++k)
#pragma unroll
      for (int j = 0; j < 4; ++j) { num[k][j] = 0.f; tn[k][j] = 0.f; }

#pragma unroll
    for (int w = 0; w < WIN; ++w) {
      const float4 t4 = *(const float4*)(tbase + w*DCOL + col);
      const float4 r4 = *(const float4*)(recent + w*DCOL + col);
      const float tt[4] = { t4.x, t4.y, t4.z, t4.w };
      const float rr[4] = { r4.x, r4.y, r4.z, r4.w };
      float rt[4], t2[4];
#pragma unroll
      for (int j = 0; j < 4; ++j) { rt[j] = rr[j]*tt[j]; t2[j] = tt[j]*tt[j]; }
#pragma unroll
      for (int k = 0; k < NK; ++k)
#pragma unroll
        for (int j = 0; j < 4; ++j) {
          num[k][j] = fmaf(k2[k][w], rt[j], num[k][j]);
          tn[k][j]  = fmaf(k2[k][w], t2[j], tn[k][j]);
        }
    }
#pragma unroll
    for (int k = 0; k < NK; ++k) {
      const float4 ri4 = *(const float4*)(rinv + k*DCOL + col);
      const float ri[4] = { ri4.x, ri4.y, ri4.z, ri4.w };
#pragma unroll
      for (int j = 0; j < 4; ++j) {
        const float tnorm = sqrtf(tn[k][j]) + EPSF;
        acc[j] += __fdividef(num[k][j] * ri[j], tnorm);
      }
    }
  }

  float a = acc[0] + acc[1] + acc[2] + acc[3];
#pragma unroll
  for (int off = 32; off > 0; off >>= 1) a += __shfl_down(a, off, 64);
  __shared__ float red[4];
  if ((tid & 63) == 0) red[tid >> 6] = a;
  __syncthreads();
  if (tid == 0) {
    const float s = red[0] + red[1] + red[2] + red[3];
    strength[p] = s * (1.0f / (NK * DCOL));
  }
}

// ---------------------------------------------------------------------------
// K2: fp32 split-K GEMM. C-tile 128x128 per block, 8x8 per thread,
// BK=16, k-major LDS [16][132] (pad 4 -> conflict-free writes, <=2/4-way reads).
// grid = (SPL, N/128, M/128). Writes partial sums to ws.
// ---------------------------------------------------------------------------
__global__ __launch_bounds__(256) void k2_gemm(
    const float* __restrict__ A, const float* __restrict__ Wt,
    float* __restrict__ part, const int ksub)
{
  __shared__ float As[16][132];
  __shared__ float Ws[16][132];
  const int sk = blockIdx.x;
  const int bn = blockIdx.y;
  const int bm = blockIdx.z;
  const int tid = threadIdx.x;
  const int tx = tid & 15, ty = tid >> 4;
  const int srow = tid >> 2;                      // 0..63
  const int skg  = tid & 3;
  const size_t k0 = (size_t)sk * ksub;

  const float* Ap = A  + (size_t)(bm*128 + srow) * DCOL + k0 + skg*4;
  const float* Wp = Wt + (size_t)(bn*128 + srow) * DCOL + k0 + skg*4;

  float c[8][8];
#pragma unroll
  for (int i = 0; i < 8; ++i)
#pragma unroll
    for (int j = 0; j < 8; ++j) c[i][j] = 0.f;

  for (int kt = 0; kt < ksub; kt += 16) {
    const float4 a0 = *(const float4*)(Ap + kt);
    const float4 a1 = *(const float4*)(Ap + (size_t)64*DCOL + kt);
    const float4 w0 = *(const float4*)(Wp + kt);
    const float4 w1 = *(const float4*)(Wp + (size_t)64*DCOL + kt);
    __syncthreads();
    {
      const float av0[4] = {a0.x,a0.y,a0.z,a0.w};
      const float av1[4] = {a1.x,a1.y,a1.z,a1.w};
      const float wv0[4] = {w0.x,w0.y,w0.z,w0.w};
      const float wv1[4] = {w1.x,w1.y,w1.z,w1.w};
#pragma unroll
      for (int j = 0; j < 4; ++j) {
        As[skg*4+j][srow]    = av0[j];
        As[skg*4+j][srow+64] = av1[j];
        Ws[skg*4+j][srow]    = wv0[j];
        Ws[skg*4+j][srow+64] = wv1[j];
      }
    }
    __syncthreads();
#pragma unroll
    for (int k = 0; k < 16; ++k) {
      const float4 x0 = *(const float4*)(&As[k][4*ty]);
      const float4 x1 = *(const float4*)(&As[k][64 + 4*ty]);
      const float4 y0 = *(const float4*)(&Ws[k][4*tx]);
      const float4 y1 = *(const float4*)(&Ws[k][64 + 4*tx]);
      const float a[8] = {x0.x,x0.y,x0.z,x0.w, x1.x,x1.y,x1.z,x1.w};
      const float w[8] = {y0.x,y0.y,y0.z,y0.w, y1.x,y1.y,y1.z,y1.w};
#pragma unroll
      for (int i = 0; i < 8; ++i)
#pragma unroll
        for (int j = 0; j < 8; ++j) c[i][j] = fmaf(a[i], w[j], c[i][j]);
    }
  }

  float* pp = part + (size_t)sk * (BATCH * PNUM);
#pragma unroll
  for (int i = 0; i < 8; ++i) {
    const int row = bm*128 + ((i < 4) ? (4*ty + i) : (64 + 4*ty + (i-4)));
    float4 lo, hi;
    lo.x=c[i][0]; lo.y=c[i][1]; lo.z=c[i][2]; lo.w=c[i][3];
    hi.x=c[i][4]; hi.y=c[i][5]; hi.z=c[i][6]; hi.w=c[i][7];
    *(float4*)(pp + (size_t)row*PNUM + bn*128 + 4*tx)      = lo;
    *(float4*)(pp + (size_t)row*PNUM + bn*128 + 64 + 4*tx) = hi;
  }
}

// ---------------------------------------------------------------------------
// K3: out[b][p] = sigmoid(strength[p] + sum_s partial[s][b][p])
// ---------------------------------------------------------------------------
__global__ __launch_bounds__(256) void k3_combine(
    const float* __restrict__ part, const float* __restrict__ strength,
    float* __restrict__ out, const int spl)
{
  const int g = blockIdx.x * 256 + threadIdx.x;
  const int i4 = g * 4;
  const int p = i4 & (PNUM - 1);
  const float4 s4 = *(const float4*)(strength + p);
  float acc[4] = { s4.x, s4.y, s4.z, s4.w };
  for (int s = 0; s < spl; ++s) {
    const float4 v = *(const float4*)(part + (size_t)s * (BATCH*PNUM) + i4);
    acc[0]+=v.x; acc[1]+=v.y; acc[2]+=v.z; acc[3]+=v.w;
  }
  float4 o;
  o.x = 1.f / (1.f + __expf(-acc[0]));
  o.y = 1.f / (1.f + __expf(-acc[1]));
  o.z = 1.f / (1.f + __expf(-acc[2]));
  o.w = 1.f / (1.f + __expf(-acc[3]));
  *(float4*)(out + i4) = o;
}

extern "C" void kernel_launch(void* const* d_in, const int* in_sizes, int n_in,
                              void* d_out, int out_size, void* d_ws, size_t ws_size,
                              hipStream_t stream)
{
  const float* spikes = (const float*)d_in[0];   // (256, 8192)
  const float* hist   = (const float*)d_in[1];   // (101, 8192)
  const float* templ  = (const float*)d_in[2];   // (1024, 10, 8192)
  const float* wts    = (const float*)d_in[3];   // (1024, 8192)
  const float* ck     = (const float*)d_in[4];   // (5, 10)
  const int*   hidx   = (const int*)d_in[5];     // scalar
  float* ws  = (float*)d_ws;
  float* out = (float*)d_out;

  int spl = 16;                                   // split-K factor
  const size_t need16 = ((size_t)WS_PART + (size_t)16 * BATCH * PNUM) * 4;
  if (ws_size < need16) spl = 4;                  // fallback: 4.5 MB of ws
  const int ksub = DCOL / spl;

  k0_prep<<<dim3(8), dim3(256), 0, stream>>>(spikes, hist, ck, hidx, ws);
  k1_strength<<<dim3(PNUM), dim3(256), 0, stream>>>(
      templ, ck, ws + WS_RECENT, ws + WS_RINV, ws + WS_STR);
  k2_gemm<<<dim3(spl, PNUM/128, BATCH/128), dim3(256), 0, stream>>>(
      spikes, wts, ws + WS_PART, ksub);
  k3_combine<<<dim3(BATCH*PNUM/(256*4)), dim3(256), 0, stream>>>(
      ws + WS_PART, ws + WS_STR, out, spl);
}